// Round 5
// baseline (7382.751 us; speedup 1.0000x reference)
//
#include <hip/hip_runtime.h>
#include <stdint.h>

#define NWG 208
#define NPHASE 259   // head t=255 at p=258

typedef __attribute__((ext_vector_type(8))) short short8;
typedef __attribute__((ext_vector_type(4))) float floatx4;
typedef __attribute__((ext_vector_type(4))) unsigned int uintx4;

static constexpr int Bb = 128, Tt = 256, Dl = 256, Hs = 512, Hb = 1024;

// ---- workspace byte layout ----
static constexpr size_t OFF_FLAGS = 0;                                   // u32[256]
static constexpr size_t OFF_B1  = 1024;                                  // f32[2048]
static constexpr size_t OFF_B2  = OFF_B1 + 2048*4;
static constexpr size_t OFF_B3  = OFF_B2 + 2048*4;                       // f32[4096]
static constexpr size_t OFF_BL  = OFF_B3 + 4096*4;                       // f32[256]
static constexpr size_t OFF_W1  = OFF_BL + 1024;                         // bf16[2048][768]
static constexpr size_t OFF_W2  = OFF_W1 + (size_t)2048*768*2;           // bf16[2048][1024]
static constexpr size_t OFF_W3  = OFF_W2 + (size_t)2048*1024*2;          // bf16[4096][1536]
static constexpr size_t OFF_WL  = OFF_W3 + (size_t)4096*1536*2;          // bf16[256][1024]
static constexpr size_t OFF_H1  = OFF_WL + (size_t)256*1024*2;           // bf16[2][128][512]
static constexpr size_t OFF_H2  = OFF_H1 + (size_t)2*128*512*2;
static constexpr size_t OFF_H3  = OFF_H2 + (size_t)2*128*512*2;          // bf16[2][128][1024]
static constexpr size_t OFF_XB  = OFF_H3 + (size_t)2*128*1024*2;         // bf16[2][128][256]
static constexpr size_t WS_NEED = OFF_XB + (size_t)2*128*256*2;          // ~20.7 MB

__device__ __forceinline__ unsigned short f2bf(float f) {
  unsigned int u = __float_as_uint(f);
  unsigned int r = (u + 0x7fffu + ((u >> 16) & 1u)) >> 16;
  return (unsigned short)r;
}
__device__ __forceinline__ float sigm(float x) { return 1.f/(1.f + __expf(-x)); }
__device__ __forceinline__ float tanh_f(float x) {
  x = fminf(fmaxf(x, -15.f), 15.f);
  float e = __expf(-2.f*x);
  return (1.f - e)/(1.f + e);
}

// coherent (write-through to LLC) stores; plain cached loads elsewhere
__device__ __forceinline__ void st_short_cg(unsigned short* p, unsigned int v) {
  asm volatile("global_store_short %0, %1, off sc0 sc1" :: "v"(p), "v"(v) : "memory");
}
__device__ __forceinline__ void st_dword_cg(void* p, unsigned int v) {
  asm volatile("global_store_dword %0, %1, off sc0 sc1" :: "v"(p), "v"(v) : "memory");
}
__device__ __forceinline__ void st_b128_cg(void* p, uintx4 v) {
  asm volatile("global_store_dwordx4 %0, %1, off sc0 sc1" :: "v"(p), "v"(v) : "memory");
}
__device__ __forceinline__ void waitcnt_vm0() {
  asm volatile("s_waitcnt vmcnt(0)" ::: "memory");
}

// ---------------- init ----------------
__global__ void lstm_init(
    const float* __restrict__ X,
    const float* __restrict__ Wih1, const float* __restrict__ Whh1,
    const float* __restrict__ bih1, const float* __restrict__ bhh1,
    const float* __restrict__ Wih2, const float* __restrict__ Whh2,
    const float* __restrict__ bih2, const float* __restrict__ bhh2,
    const float* __restrict__ Wih3, const float* __restrict__ Whh3,
    const float* __restrict__ bih3, const float* __restrict__ bhh3,
    const float* __restrict__ Wlin, const float* __restrict__ blin,
    unsigned char* __restrict__ ws)
{
  size_t i0 = (size_t)blockIdx.x*blockDim.x + threadIdx.x;
  size_t np = (size_t)gridDim.x*blockDim.x;

  unsigned int* fl = (unsigned int*)(ws + OFF_FLAGS);
  for (size_t i = i0; i < 256; i += np) fl[i] = (i < NWG) ? 0u : 0xFFFFFFFFu;

  float* b1 = (float*)(ws + OFF_B1);
  float* b2 = (float*)(ws + OFF_B2);
  float* b3 = (float*)(ws + OFF_B3);
  float* bl = (float*)(ws + OFF_BL);
  for (size_t i = i0; i < 2048; i += np) b1[i] = bih1[i] + bhh1[i];
  for (size_t i = i0; i < 2048; i += np) b2[i] = bih2[i] + bhh2[i];
  for (size_t i = i0; i < 4096; i += np) b3[i] = bih3[i] + bhh3[i];
  for (size_t i = i0; i < 256;  i += np) bl[i] = blin[i];

  unsigned short* w1 = (unsigned short*)(ws + OFF_W1);
  unsigned short* w2 = (unsigned short*)(ws + OFF_W2);
  unsigned short* w3 = (unsigned short*)(ws + OFF_W3);
  unsigned short* wl = (unsigned short*)(ws + OFF_WL);
  for (size_t i = i0; i < (size_t)2048*768; i += np) {
    size_t r = i/768, k = i - r*768;
    float v = (k < 256) ? Wih1[r*256 + k] : Whh1[r*512 + (k - 256)];
    w1[i] = f2bf(v);
  }
  for (size_t i = i0; i < (size_t)2048*1024; i += np) {
    size_t r = i >> 10, k = i & 1023;
    float v = (k < 512) ? Wih2[r*512 + k] : Whh2[r*512 + (k - 512)];
    w2[i] = f2bf(v);
  }
  for (size_t i = i0; i < (size_t)4096*1536; i += np) {
    size_t r = i/1536, k = i - r*1536;
    float v = (k < 512) ? Wih3[r*512 + k] : Whh3[r*1024 + (k - 512)];
    w3[i] = f2bf(v);
  }
  for (size_t i = i0; i < (size_t)256*1024; i += np) wl[i] = f2bf(Wlin[i]);

  unsigned short* rings = (unsigned short*)(ws + OFF_H1);
  for (size_t i = i0; i < (size_t)(2*128*512 + 2*128*512 + 2*128*1024); i += np) rings[i] = 0;

  // stage x(t=0) into XB slot 0
  unsigned short* xb = (unsigned short*)(ws + OFF_XB);
  for (size_t i = i0; i < (size_t)128*256; i += np) {
    size_t b = i >> 8, d = i & 255;
    xb[b*256 + d] = f2bf(X[(b*(size_t)Tt + 0)*Dl + d]);
  }
}

// ---------------- per-layer phase: full-K per wave, gate shuffle-exchange ----------------
// TYPE0 (L1): K=768, segA=XB(pitch256,KB1=256), segB=h1(512); MF=4
// TYPE1 (L2): K=1024, segA=h1(512,KB1=512), segB=h2(512); MF=4
// TYPE2 (L3): K=1536, segA=h2(512,KB1=512), segB=h3(1024); MF=2
template<int TYPE>
__device__ __forceinline__ void layer_phase(
    const unsigned short* __restrict__ segA,
    const unsigned short* __restrict__ segB,
    unsigned short* __restrict__ hout,
    const unsigned char* __restrict__ smem,
    const float* __restrict__ bias_r,     // [2] per-lane preloaded
    float (&creg)[4][2][4],
    int U0, int wv, int lane)
{
  constexpr int K    = (TYPE==0 ? 768 : TYPE==1 ? 1024 : 1536);
  constexpr int KB1  = (TYPE==0 ? 256 : 512);
  constexpr int PA   = (TYPE==0 ? 256 : 512);
  constexpr int PB   = (TYPE==2 ? 1024 : 512);
  constexpr int HH   = (TYPE==2 ? 1024 : 512);
  constexpr int MF   = (TYPE==2 ? 2 : 4);
  constexpr int NCH  = K/128;
  const int l15 = lane & 15;
  const int klo = (lane >> 4) << 3;
  const int g   = l15 >> 2;
  const int mbase = (TYPE==2 ? wv*32 : (wv&1)*64);
  const int nfb   = (TYPE==2 ? 0 : (wv>>1)*2);

  const unsigned short* pa[MF];
  const unsigned short* pb[MF];
  #pragma unroll
  for (int mf = 0; mf < MF; ++mf) {
    const int row = mbase + mf*16 + l15;
    pa[mf] = segA + (size_t)row*PA + klo;
    pb[mf] = segB + (size_t)row*PB + klo - KB1;
  }
  int rowbyte[2], xr[2];
  #pragma unroll
  for (int nf = 0; nf < 2; ++nf) {
    const int rp = (nfb + nf)*16 + l15;
    rowbyte[nf] = rp*(K*2);
    xr[nf] = (rp & 7) << 4;
  }
  const int klobyte = klo*2;

  floatx4 acc[MF][2];
  #pragma unroll
  for (int mf = 0; mf < MF; ++mf)
    #pragma unroll
    for (int nf = 0; nf < 2; ++nf) {
      float bv = bias_r[nf];
      floatx4 b4 = {bv, bv, bv, bv};
      acc[mf][nf] = b4;
    }

  short8 A0[4][MF], A1[4][MF];
  auto LOADC = [&](int c, short8 (&A)[4][MF]) {
    #pragma unroll
    for (int ks = 0; ks < 4; ++ks) {
      const int kb = c*128 + ks*32;
      #pragma unroll
      for (int mf = 0; mf < MF; ++mf) {
        const unsigned short* p = (kb < KB1 ? pa[mf] : pb[mf]) + kb;
        A[ks][mf] = *(const short8*)p;
      }
    }
  };
  auto MM = [&](int c, short8 (&A)[4][MF]) {
    #pragma unroll
    for (int ks = 0; ks < 4; ++ks) {
      const int kb = c*128 + ks*32;
      short8 bf[2];
      #pragma unroll
      for (int nf = 0; nf < 2; ++nf)
        bf[nf] = *(const short8*)(smem + rowbyte[nf] + ((kb*2 + klobyte) ^ xr[nf]));
      #pragma unroll
      for (int mf = 0; mf < MF; ++mf)
        #pragma unroll
        for (int nf = 0; nf < 2; ++nf)
          acc[mf][nf] = __builtin_amdgcn_mfma_f32_16x16x32_bf16(A[ks][mf], bf[nf], acc[mf][nf], 0, 0, 0);
    }
  };

  LOADC(0, A0);
  #pragma unroll 1
  for (int ch = 0; ch < NCH; ch += 2) {
    LOADC(ch + 1, A1);
    MM(ch, A0);
    if (ch + 2 < NCH) LOADC(ch + 2, A0);
    MM(ch + 1, A1);
  }

  // cell update: lanes of a unit-quad exchange gates via xor-4/8/12 shuffles
  #pragma unroll
  for (int nf = 0; nf < 2; ++nf) {
    const int u = U0 + (nfb + nf)*4 + (l15 & 3);
    #pragma unroll
    for (int mf = 0; mf < MF; ++mf) {
      float h4[4];
      #pragma unroll
      for (int j = 0; j < 4; ++j) {
        float s0  = acc[mf][nf][j];
        float s4  = __shfl_xor(s0, 4);
        float s8  = __shfl_xor(s0, 8);
        float s12 = __shfl_xor(s0, 12);
        float iv = (g==0)?s0 :(g==1)?s4 :(g==2)?s8 :s12;
        float fv = (g==0)?s4 :(g==1)?s0 :(g==2)?s12:s8;
        float gv = (g==0)?s8 :(g==1)?s12:(g==2)?s0 :s4;
        float ov = (g==0)?s12:(g==1)?s8 :(g==2)?s4 :s0;
        float c  = sigm(fv)*creg[mf][nf][j] + sigm(iv)*tanh_f(gv);
        creg[mf][nf][j] = c;
        h4[j] = sigm(ov)*tanh_f(c);
      }
      float hs = (g==0)?h4[0]:(g==1)?h4[1]:(g==2)?h4[2]:h4[3];
      const int row = mbase + mf*16 + ((lane >> 4) << 2) + g;
      st_short_cg(hout + (size_t)row*HH + u, (unsigned int)f2bf(hs));
    }
  }
}

// ---------------- persistent kernel ----------------
// wg 0..31: L1 (t=p) | 32..63: L2 (t=p-1) | 64..191: L3 (t=p-2) | 192..207: head (t=p-3) + x-stage (p+1)
__global__ void __launch_bounds__(256, 1)
lstm_persist(const float* __restrict__ X, float* __restrict__ out,
             unsigned char* __restrict__ ws)
{
  extern __shared__ unsigned char smem[];

  const int tid  = threadIdx.x;
  const int lane = tid & 63;
  const int wv   = tid >> 6;
  const int wg   = blockIdx.x;
  const int l15  = lane & 15;
  const int klo  = (lane >> 4) << 3;

  unsigned int* flags = (unsigned int*)(ws + OFF_FLAGS);
  const float* bias1 = (const float*)(ws + OFF_B1);
  const float* bias2 = (const float*)(ws + OFF_B2);
  const float* bias3 = (const float*)(ws + OFF_B3);
  const float* biasl = (const float*)(ws + OFF_BL);
  const unsigned short* W1 = (const unsigned short*)(ws + OFF_W1);
  const unsigned short* W2 = (const unsigned short*)(ws + OFF_W2);
  const unsigned short* W3 = (const unsigned short*)(ws + OFF_W3);
  const unsigned short* WL = (const unsigned short*)(ws + OFF_WL);
  unsigned short* h1r = (unsigned short*)(ws + OFF_H1);
  unsigned short* h2r = (unsigned short*)(ws + OFF_H2);
  unsigned short* h3r = (unsigned short*)(ws + OFF_H3);
  unsigned short* Xb  = (unsigned short*)(ws + OFF_XB);

  // role decode
  int type, U0 = 0, osec = 0, K = 0, WROWS = 0, HGATE = 0;
  const unsigned short* Wg = nullptr; const float* biasp = nullptr;
  if (wg < 32)        { type = 0; U0 = wg*16;        Wg = W1; biasp = bias1; K = 768;  WROWS = 64; HGATE = 512; }
  else if (wg < 64)   { type = 1; U0 = (wg-32)*16;   Wg = W2; biasp = bias2; K = 1024; WROWS = 64; HGATE = 512; }
  else if (wg < 192)  { type = 2; U0 = (wg-64)*8;    Wg = W3; biasp = bias3; K = 1536; WROWS = 32; HGATE = 1024; }
  else                { type = 3; osec = (wg-192)*16; Wg = WL; K = 1024; WROWS = 16; }

  // prologue: weight slice -> LDS (packed rows: quad=4 units x 4 gates), XOR-swizzled
  {
    const int rowchunks = K >> 3;
    for (int idx = tid; idx < WROWS*rowchunks; idx += 256) {
      const int rp = idx / rowchunks, kc = idx - rp*rowchunks;
      int R;
      if (type == 3) R = osec + rp;
      else {
        const int c = rp & 15;
        R = (c >> 2)*HGATE + U0 + (rp >> 4)*4 + (c & 3);
      }
      uintx4 v = *(const uintx4*)(Wg + (size_t)R*K + kc*8);
      const int db = rp*(K*2) + ((kc*16) ^ ((rp & 7) << 4));
      *(uintx4*)(smem + db) = v;
    }
  }

  // per-lane bias preload (constant across phases)
  float bias_r[2] = {0.f, 0.f};
  if (type < 3) {
    const int g   = l15 >> 2;
    const int nfb = (type == 2 ? 0 : (wv >> 1)*2);
    #pragma unroll
    for (int nf = 0; nf < 2; ++nf) {
      const int u = U0 + (nfb + nf)*4 + (l15 & 3);
      bias_r[nf] = biasp[g*HGATE + u];
    }
  } else {
    bias_r[0] = biasl[osec + l15];
  }

  float creg[4][2][4];
  #pragma unroll
  for (int a = 0; a < 4; ++a)
    #pragma unroll
    for (int b = 0; b < 2; ++b)
      #pragma unroll
      for (int c = 0; c < 4; ++c) creg[a][b][c] = 0.f;

  __syncthreads();

  for (int p = 0; p < NPHASE; ++p) {
    if (type == 0) {
      const int t = p;
      if (t < Tt)
        layer_phase<0>(Xb + (size_t)(t&1)*Bb*Dl,
                       h1r + (size_t)((t-1)&1)*Bb*Hs,
                       h1r + (size_t)(t&1)*Bb*Hs,
                       smem, bias_r, creg, U0, wv, lane);
    } else if (type == 1) {
      const int t = p - 1;
      if (t >= 0 && t < Tt)
        layer_phase<1>(h1r + (size_t)(t&1)*Bb*Hs,
                       h2r + (size_t)((t-1)&1)*Bb*Hs,
                       h2r + (size_t)(t&1)*Bb*Hs,
                       smem, bias_r, creg, U0, wv, lane);
    } else if (type == 2) {
      const int t = p - 2;
      if (t >= 0 && t < Tt)
        layer_phase<2>(h2r + (size_t)(t&1)*Bb*Hs,
                       h3r + (size_t)((t-1)&1)*Bb*Hb,
                       h3r + (size_t)(t&1)*Bb*Hb,
                       smem, bias_r, creg, U0, wv, lane);
    } else {
      // ---- x staging for t = p+1 ----
      if (p + 1 < Tt) {
        const int tx = p + 1;
        const int j = wg - 192;
        const int i = tid*8;
        const int row = j*8 + (i >> 8);
        const int d = i & 255;
        const float* xp = X + ((size_t)row*Tt + tx)*Dl + d;
        float4 f0 = *(const float4*)xp;
        float4 f1 = *(const float4*)(xp + 4);
        uintx4 pk;
        pk[0] = (unsigned int)f2bf(f0.x) | ((unsigned int)f2bf(f0.y) << 16);
        pk[1] = (unsigned int)f2bf(f0.z) | ((unsigned int)f2bf(f0.w) << 16);
        pk[2] = (unsigned int)f2bf(f1.x) | ((unsigned int)f2bf(f1.y) << 16);
        pk[3] = (unsigned int)f2bf(f1.z) | ((unsigned int)f2bf(f1.w) << 16);
        st_b128_cg(Xb + (size_t)(tx&1)*Bb*Dl + (size_t)row*Dl + d, pk);
      }
      // ---- linear head, t = p-3: per WG m128 x n16 ----
      const int to = p - 3;
      if (to >= 0 && to < Tt) {
        const unsigned short* hA = h3r + (size_t)(to&1)*Bb*Hb;
        const unsigned short* pa[2];
        #pragma unroll
        for (int mf = 0; mf < 2; ++mf) {
          const int row = wv*32 + mf*16 + l15;
          pa[mf] = hA + (size_t)row*Hb + klo;
        }
        const int rowbyte = l15*2048;
        const int xr = (l15 & 7) << 4;
        const int klobyte = klo*2;
        floatx4 oacc[2];
        {
          floatx4 b4 = {bias_r[0], bias_r[0], bias_r[0], bias_r[0]};
          oacc[0] = b4; oacc[1] = b4;
        }
        short8 A0[4][2], A1[4][2];
        auto HLOAD = [&](int c, short8 (&A)[4][2]) {
          #pragma unroll
          for (int ks = 0; ks < 4; ++ks)
            #pragma unroll
            for (int mf = 0; mf < 2; ++mf)
              A[ks][mf] = *(const short8*)(pa[mf] + c*128 + ks*32);
        };
        auto HMM = [&](int c, short8 (&A)[4][2]) {
          #pragma unroll
          for (int ks = 0; ks < 4; ++ks) {
            const int kb = c*128 + ks*32;
            short8 bw = *(const short8*)(smem + rowbyte + ((kb*2 + klobyte) ^ xr));
            #pragma unroll
            for (int mf = 0; mf < 2; ++mf)
              oacc[mf] = __builtin_amdgcn_mfma_f32_16x16x32_bf16(A[ks][mf], bw, oacc[mf], 0, 0, 0);
          }
        };
        HLOAD(0, A0);
        #pragma unroll 1
        for (int ch = 0; ch < 8; ch += 2) {
          HLOAD(ch + 1, A1);
          HMM(ch, A0);
          if (ch + 2 < 8) HLOAD(ch + 2, A0);
          HMM(ch + 1, A1);
        }
        const int col = osec + l15;
        #pragma unroll
        for (int mf = 0; mf < 2; ++mf) {
          const int b0 = wv*32 + mf*16 + ((lane >> 4) << 2);
          #pragma unroll
          for (int j = 0; j < 4; ++j)
            st_dword_cg(out + ((size_t)to*Bb + b0 + j)*Dl + col,
                        __float_as_uint(oacc[mf][j]));
        }
      }
    }

    // ---- grid barrier + cache acquire ----
    if (p < NPHASE - 1) {
      waitcnt_vm0();
      __syncthreads();
      const unsigned int tgt = (unsigned int)(p + 1);
      if (tid == 0) st_dword_cg(flags + wg, tgt);
      if (tid < 64) {
        uintx4 f;
        for (;;) {
          asm volatile("global_load_dwordx4 %0, %1, off sc0 sc1\n\t"
                       "s_waitcnt vmcnt(0)"
                       : "=v"(f) : "v"(flags + lane*4) : "memory");
          if (f[0] >= tgt && f[1] >= tgt && f[2] >= tgt && f[3] >= tgt) break;
          __builtin_amdgcn_s_sleep(4);
        }
      }
      __syncthreads();
      __builtin_amdgcn_fence(__ATOMIC_ACQUIRE, "agent");  // invalidate L1/L2 -> re-read fresh from LLC
    }
  }
}

extern "C" void kernel_launch(void* const* d_in, const int* in_sizes, int n_in,
                              void* d_out, int out_size, void* d_ws, size_t ws_size,
                              hipStream_t stream)
{
  if (ws_size < WS_NEED) return;

  const float* X    = (const float*)d_in[0];
  const float* Wih1 = (const float*)d_in[1];
  const float* Whh1 = (const float*)d_in[2];
  const float* bih1 = (const float*)d_in[3];
  const float* bhh1 = (const float*)d_in[4];
  const float* Wih2 = (const float*)d_in[5];
  const float* Whh2 = (const float*)d_in[6];
  const float* bih2 = (const float*)d_in[7];
  const float* bhh2 = (const float*)d_in[8];
  const float* Wih3 = (const float*)d_in[9];
  const float* Whh3 = (const float*)d_in[10];
  const float* bih3 = (const float*)d_in[11];
  const float* bhh3 = (const float*)d_in[12];
  const float* Wlin = (const float*)d_in[13];
  const float* blin = (const float*)d_in[14];
  unsigned char* ws = (unsigned char*)d_ws;

  lstm_init<<<2048, 256, 0, stream>>>(X, Wih1, Whh1, bih1, bhh1,
                                      Wih2, Whh2, bih2, bhh2,
                                      Wih3, Whh3, bih3, bhh3,
                                      Wlin, blin, ws);
  lstm_persist<<<NWG, 256, 131072, stream>>>(X, (float*)d_out, ws);
}

// Round 8
// 6227.345 us; speedup vs baseline: 1.1855x; 1.1855x over previous
//
#include <hip/hip_runtime.h>
#include <stdint.h>

#define NWG 208
#define NPHASE 259   // head t=255 at p=258

typedef __attribute__((ext_vector_type(8))) short short8;
typedef __attribute__((ext_vector_type(4))) float floatx4;
typedef __attribute__((ext_vector_type(4))) unsigned int uintx4;

static constexpr int Bb = 128, Tt = 256, Dl = 256, Hs = 512, Hb = 1024;

// ---- fixed workspace header ----
static constexpr size_t OFF_FLAGS = 0;                                   // u32[256]
static constexpr size_t OFF_B1  = 1024;                                  // f32[2048]
static constexpr size_t OFF_B2  = OFF_B1 + 2048*4;
static constexpr size_t OFF_B3  = OFF_B2 + 2048*4;                       // f32[4096]
static constexpr size_t OFF_BL  = OFF_B3 + 4096*4;                       // f32[256]
static constexpr size_t OFF_W1  = OFF_BL + 1024;                         // bf16[2048][768]
static constexpr size_t OFF_W2  = OFF_W1 + (size_t)2048*768*2;           // bf16[2048][1024]
static constexpr size_t OFF_W3  = OFF_W2 + (size_t)2048*1024*2;          // bf16[4096][1536]
static constexpr size_t OFF_WL  = OFF_W3 + (size_t)4096*1536*2;          // bf16[256][1024]
static constexpr size_t FIXED_END = OFF_WL + (size_t)256*1024*2;

// rings (row-major, r5-proven layout), depth D: h1[D][128][512], h2 same,
// h3[D][128][1024], x[D][128][256]
template<int D> struct Lay {
  static constexpr size_t H1  = FIXED_END;
  static constexpr size_t H2  = H1 + (size_t)D*Bb*Hs*2;
  static constexpr size_t H3  = H2 + (size_t)D*Bb*Hs*2;
  static constexpr size_t XB  = H3 + (size_t)D*Bb*Hb*2;
  static constexpr size_t END = XB + (size_t)D*Bb*Dl*2;
};

__device__ __forceinline__ unsigned short f2bf(float f) {
  unsigned int u = __float_as_uint(f);
  unsigned int r = (u + 0x7fffu + ((u >> 16) & 1u)) >> 16;
  return (unsigned short)r;
}
__device__ __forceinline__ float sigm(float x) { return 1.f/(1.f + __expf(-x)); }
__device__ __forceinline__ float tanh_f(float x) {
  x = fminf(fmaxf(x, -15.f), 15.f);
  float e = __expf(-2.f*x);
  return (1.f - e)/(1.f + e);
}

// coherent (write-through to LLC) stores; plain cached loads elsewhere
__device__ __forceinline__ void st_short_cg(unsigned short* p, unsigned int v) {
  asm volatile("global_store_short %0, %1, off sc0 sc1" :: "v"(p), "v"(v) : "memory");
}
__device__ __forceinline__ void st_dword_cg(void* p, unsigned int v) {
  asm volatile("global_store_dword %0, %1, off sc0 sc1" :: "v"(p), "v"(v) : "memory");
}
__device__ __forceinline__ void st_b128_cg(void* p, uintx4 v) {
  asm volatile("global_store_dwordx4 %0, %1, off sc0 sc1" :: "v"(p), "v"(v) : "memory");
}
__device__ __forceinline__ void waitcnt_vm0() {
  asm volatile("s_waitcnt vmcnt(0)" ::: "memory");
}

// ---------------- init ----------------
template<int D>
__global__ void lstm_init(
    const float* __restrict__ X,
    const float* __restrict__ Wih1, const float* __restrict__ Whh1,
    const float* __restrict__ bih1, const float* __restrict__ bhh1,
    const float* __restrict__ Wih2, const float* __restrict__ Whh2,
    const float* __restrict__ bih2, const float* __restrict__ bhh2,
    const float* __restrict__ Wih3, const float* __restrict__ Whh3,
    const float* __restrict__ bih3, const float* __restrict__ bhh3,
    const float* __restrict__ Wlin, const float* __restrict__ blin,
    unsigned char* __restrict__ ws)
{
  size_t i0 = (size_t)blockIdx.x*blockDim.x + threadIdx.x;
  size_t np = (size_t)gridDim.x*blockDim.x;

  unsigned int* fl = (unsigned int*)(ws + OFF_FLAGS);
  for (size_t i = i0; i < 256; i += np) fl[i] = (i < NWG) ? 0u : 0xFFFFFFFFu;

  float* b1 = (float*)(ws + OFF_B1);
  float* b2 = (float*)(ws + OFF_B2);
  float* b3 = (float*)(ws + OFF_B3);
  float* bl = (float*)(ws + OFF_BL);
  for (size_t i = i0; i < 2048; i += np) b1[i] = bih1[i] + bhh1[i];
  for (size_t i = i0; i < 2048; i += np) b2[i] = bih2[i] + bhh2[i];
  for (size_t i = i0; i < 4096; i += np) b3[i] = bih3[i] + bhh3[i];
  for (size_t i = i0; i < 256;  i += np) bl[i] = blin[i];

  unsigned short* w1 = (unsigned short*)(ws + OFF_W1);
  unsigned short* w2 = (unsigned short*)(ws + OFF_W2);
  unsigned short* w3 = (unsigned short*)(ws + OFF_W3);
  unsigned short* wl = (unsigned short*)(ws + OFF_WL);
  for (size_t i = i0; i < (size_t)2048*768; i += np) {
    size_t r = i/768, k = i - r*768;
    float v = (k < 256) ? Wih1[r*256 + k] : Whh1[r*512 + (k - 256)];
    w1[i] = f2bf(v);
  }
  for (size_t i = i0; i < (size_t)2048*1024; i += np) {
    size_t r = i >> 10, k = i & 1023;
    float v = (k < 512) ? Wih2[r*512 + k] : Whh2[r*512 + (k - 512)];
    w2[i] = f2bf(v);
  }
  for (size_t i = i0; i < (size_t)4096*1536; i += np) {
    size_t r = i/1536, k = i - r*1536;
    float v = (k < 512) ? Wih3[r*512 + k] : Whh3[r*1024 + (k - 512)];
    w3[i] = f2bf(v);
  }
  for (size_t i = i0; i < (size_t)256*1024; i += np) wl[i] = f2bf(Wlin[i]);

  // zero ALL slots of all h rings (covers t=-1 slot D-1 and removes edge cases)
  unsigned short* rings = (unsigned short*)(ws + Lay<D>::H1);
  const size_t nring = (size_t)D*Bb*Hs + (size_t)D*Bb*Hs + (size_t)D*Bb*Hb;
  for (size_t i = i0; i < nring; i += np) rings[i] = 0;

  // stage x(t=0) into XB slot 0 (row-major [row][256])
  unsigned short* xb0 = (unsigned short*)(ws + Lay<D>::XB);
  for (size_t i = i0; i < (size_t)Bb*Dl; i += np) {
    size_t b = i >> 8, d = i & 255;
    xb0[b*256 + d] = f2bf(X[(b*(size_t)Tt + 0)*Dl + d]);
  }
}

// ---------------- per-layer phase (r5-verbatim): full-K per wave, gate shuffle-exchange ----------------
// TYPE0 (L1): K=768, segA=XB(pitch256,KB1=256), segB=h1(512); MF=4
// TYPE1 (L2): K=1024, segA=h1(512,KB1=512), segB=h2(512); MF=4
// TYPE2 (L3): K=1536, segA=h2(512,KB1=512), segB=h3(1024); MF=2
template<int TYPE>
__device__ __forceinline__ void layer_phase(
    const unsigned short* __restrict__ segA,
    const unsigned short* __restrict__ segB,
    unsigned short* __restrict__ hout,
    const unsigned char* __restrict__ smem,
    const float* __restrict__ bias_r,
    float (&creg)[4][2][4],
    int U0, int wv, int lane)
{
  constexpr int K    = (TYPE==0 ? 768 : TYPE==1 ? 1024 : 1536);
  constexpr int KB1  = (TYPE==0 ? 256 : 512);
  constexpr int PA   = (TYPE==0 ? 256 : 512);
  constexpr int PB   = (TYPE==2 ? 1024 : 512);
  constexpr int HH   = (TYPE==2 ? 1024 : 512);
  constexpr int MF   = (TYPE==2 ? 2 : 4);
  constexpr int NCH  = K/128;
  const int l15 = lane & 15;
  const int klo = (lane >> 4) << 3;
  const int g   = l15 >> 2;
  const int mbase = (TYPE==2 ? wv*32 : (wv&1)*64);
  const int nfb   = (TYPE==2 ? 0 : (wv>>1)*2);

  const unsigned short* pa[MF];
  const unsigned short* pb[MF];
  #pragma unroll
  for (int mf = 0; mf < MF; ++mf) {
    const int row = mbase + mf*16 + l15;
    pa[mf] = segA + (size_t)row*PA + klo;
    pb[mf] = segB + (size_t)row*PB + klo - KB1;
  }
  int rowbyte[2], xr[2];
  #pragma unroll
  for (int nf = 0; nf < 2; ++nf) {
    const int rp = (nfb + nf)*16 + l15;
    rowbyte[nf] = rp*(K*2);
    xr[nf] = (rp & 7) << 4;
  }
  const int klobyte = klo*2;

  floatx4 acc[MF][2];
  #pragma unroll
  for (int mf = 0; mf < MF; ++mf)
    #pragma unroll
    for (int nf = 0; nf < 2; ++nf) {
      float bv = bias_r[nf];
      floatx4 b4 = {bv, bv, bv, bv};
      acc[mf][nf] = b4;
    }

  short8 A0[4][MF], A1[4][MF];
  auto LOADC = [&](int c, short8 (&A)[4][MF]) {
    #pragma unroll
    for (int ks = 0; ks < 4; ++ks) {
      const int kb = c*128 + ks*32;
      #pragma unroll
      for (int mf = 0; mf < MF; ++mf) {
        const unsigned short* p = (kb < KB1 ? pa[mf] : pb[mf]) + kb;
        A[ks][mf] = *(const short8*)p;
      }
    }
  };
  auto MM = [&](int c, short8 (&A)[4][MF]) {
    #pragma unroll
    for (int ks = 0; ks < 4; ++ks) {
      const int kb = c*128 + ks*32;
      short8 bf[2];
      #pragma unroll
      for (int nf = 0; nf < 2; ++nf)
        bf[nf] = *(const short8*)(smem + rowbyte[nf] + ((kb*2 + klobyte) ^ xr[nf]));
      #pragma unroll
      for (int mf = 0; mf < MF; ++mf)
        #pragma unroll
        for (int nf = 0; nf < 2; ++nf)
          acc[mf][nf] = __builtin_amdgcn_mfma_f32_16x16x32_bf16(A[ks][mf], bf[nf], acc[mf][nf], 0, 0, 0);
    }
  };

  LOADC(0, A0);
  #pragma unroll 1
  for (int ch = 0; ch < NCH; ch += 2) {
    LOADC(ch + 1, A1);
    MM(ch, A0);
    if (ch + 2 < NCH) LOADC(ch + 2, A0);
    MM(ch + 1, A1);
  }

  // cell update: lanes of a unit-quad exchange gates via xor-4/8/12 shuffles
  #pragma unroll
  for (int nf = 0; nf < 2; ++nf) {
    const int u = U0 + (nfb + nf)*4 + (l15 & 3);
    #pragma unroll
    for (int mf = 0; mf < MF; ++mf) {
      float h4[4];
      #pragma unroll
      for (int j = 0; j < 4; ++j) {
        float s0  = acc[mf][nf][j];
        float s4  = __shfl_xor(s0, 4);
        float s8  = __shfl_xor(s0, 8);
        float s12 = __shfl_xor(s0, 12);
        float iv = (g==0)?s0 :(g==1)?s4 :(g==2)?s8 :s12;
        float fv = (g==0)?s4 :(g==1)?s0 :(g==2)?s12:s8;
        float gv = (g==0)?s8 :(g==1)?s12:(g==2)?s0 :s4;
        float ov = (g==0)?s12:(g==1)?s8 :(g==2)?s4 :s0;
        float c  = sigm(fv)*creg[mf][nf][j] + sigm(iv)*tanh_f(gv);
        creg[mf][nf][j] = c;
        h4[j] = sigm(ov)*tanh_f(c);
      }
      float hs = (g==0)?h4[0]:(g==1)?h4[1]:(g==2)?h4[2]:h4[3];
      const int row = mbase + mf*16 + ((lane >> 4) << 2) + g;
      st_short_cg(hout + (size_t)row*HH + u, (unsigned int)f2bf(hs));
    }
  }
}

// ---------------- persistent kernel ----------------
// wg 0..31: L1 (t=p) | 32..63: L2 (t=p-1) | 64..191: L3 (t=p-2) | 192..207: head (t=p-3) + x-stage (p+1)
template<int D>
__global__ void __launch_bounds__(256, 1)
lstm_persist(const float* __restrict__ X, float* __restrict__ out,
             unsigned char* __restrict__ ws)
{
  extern __shared__ unsigned char smem[];

  __builtin_amdgcn_fence(__ATOMIC_ACQUIRE, "agent");  // clear any pre-dispatch stale lines (cheap, once)

  const int tid  = threadIdx.x;
  const int lane = tid & 63;
  const int wv   = tid >> 6;
  const int wg   = blockIdx.x;
  const int l15  = lane & 15;
  const int klo  = (lane >> 4) << 3;

  unsigned int* flags = (unsigned int*)(ws + OFF_FLAGS);
  const float* bias1 = (const float*)(ws + OFF_B1);
  const float* bias2 = (const float*)(ws + OFF_B2);
  const float* bias3 = (const float*)(ws + OFF_B3);
  const float* biasl = (const float*)(ws + OFF_BL);
  const unsigned short* W1 = (const unsigned short*)(ws + OFF_W1);
  const unsigned short* W2 = (const unsigned short*)(ws + OFF_W2);
  const unsigned short* W3 = (const unsigned short*)(ws + OFF_W3);
  const unsigned short* WL = (const unsigned short*)(ws + OFF_WL);
  unsigned short* h1r = (unsigned short*)(ws + Lay<D>::H1);
  unsigned short* h2r = (unsigned short*)(ws + Lay<D>::H2);
  unsigned short* h3r = (unsigned short*)(ws + Lay<D>::H3);
  unsigned short* Xb  = (unsigned short*)(ws + Lay<D>::XB);

  auto slot = [](int t) -> size_t { return (size_t)(t & (D - 1)); };
  const size_t HSs = (size_t)Bb*Hs, HBs = (size_t)Bb*Hb, XBs = (size_t)Bb*Dl;

  // role decode
  int type, U0 = 0, osec = 0, K = 0, WROWS = 0, HGATE = 0;
  const unsigned short* Wg = nullptr; const float* biasp = nullptr;
  if (wg < 32)        { type = 0; U0 = wg*16;        Wg = W1; biasp = bias1; K = 768;  WROWS = 64; HGATE = 512; }
  else if (wg < 64)   { type = 1; U0 = (wg-32)*16;   Wg = W2; biasp = bias2; K = 1024; WROWS = 64; HGATE = 512; }
  else if (wg < 192)  { type = 2; U0 = (wg-64)*8;    Wg = W3; biasp = bias3; K = 1536; WROWS = 32; HGATE = 1024; }
  else                { type = 3; osec = (wg-192)*16; Wg = WL; K = 1024; WROWS = 16; }

  // prologue: weight slice -> LDS (packed rows: quad=4 units x 4 gates), XOR-swizzled
  {
    const int rowchunks = K >> 3;
    for (int idx = tid; idx < WROWS*rowchunks; idx += 256) {
      const int rp = idx / rowchunks, kc = idx - rp*rowchunks;
      int R;
      if (type == 3) R = osec + rp;
      else {
        const int c = rp & 15;
        R = (c >> 2)*HGATE + U0 + (rp >> 4)*4 + (c & 3);
      }
      uintx4 v = *(const uintx4*)(Wg + (size_t)R*K + kc*8);
      const int db = rp*(K*2) + ((kc*16) ^ ((rp & 7) << 4));
      *(uintx4*)(smem + db) = v;
    }
  }

  // per-lane bias preload (constant across phases)
  float bias_r[2] = {0.f, 0.f};
  if (type < 3) {
    const int g   = l15 >> 2;
    const int nfb = (type == 2 ? 0 : (wv >> 1)*2);
    #pragma unroll
    for (int nf = 0; nf < 2; ++nf) {
      const int u = U0 + (nfb + nf)*4 + (l15 & 3);
      bias_r[nf] = biasp[g*HGATE + u];
    }
  } else {
    bias_r[0] = biasl[osec + l15];
  }

  float creg[4][2][4];
  #pragma unroll
  for (int a = 0; a < 4; ++a)
    #pragma unroll
    for (int b = 0; b < 2; ++b)
      #pragma unroll
      for (int c = 0; c < 4; ++c) creg[a][b][c] = 0.f;

  __syncthreads();

  for (int p = 0; p < NPHASE; ++p) {
    if (type == 0) {
      const int t = p;
      if (t < Tt)
        layer_phase<0>(Xb + slot(t)*XBs,
                       h1r + slot(t-1)*HSs,
                       h1r + slot(t)*HSs,
                       smem, bias_r, creg, U0, wv, lane);
    } else if (type == 1) {
      const int t = p - 1;
      if (t >= 0 && t < Tt)
        layer_phase<1>(h1r + slot(t)*HSs,
                       h2r + slot(t-1)*HSs,
                       h2r + slot(t)*HSs,
                       smem, bias_r, creg, U0, wv, lane);
    } else if (type == 2) {
      const int t = p - 2;
      if (t >= 0 && t < Tt)
        layer_phase<2>(h2r + slot(t)*HSs,
                       h3r + slot(t-1)*HBs,
                       h3r + slot(t)*HBs,
                       smem, bias_r, creg, U0, wv, lane);
    } else {
      // ---- x staging for t = p+1 ----
      if (p + 1 < Tt) {
        const int tx = p + 1;
        const int j = wg - 192;
        const int i = tid*8;
        const int row = j*8 + (i >> 8);
        const int d = i & 255;
        const float* xp = X + ((size_t)row*Tt + tx)*Dl + d;
        float4 f0 = *(const float4*)xp;
        float4 f1 = *(const float4*)(xp + 4);
        uintx4 pk;
        pk[0] = (unsigned int)f2bf(f0.x) | ((unsigned int)f2bf(f0.y) << 16);
        pk[1] = (unsigned int)f2bf(f0.z) | ((unsigned int)f2bf(f0.w) << 16);
        pk[2] = (unsigned int)f2bf(f1.x) | ((unsigned int)f2bf(f1.y) << 16);
        pk[3] = (unsigned int)f2bf(f1.z) | ((unsigned int)f2bf(f1.w) << 16);
        st_b128_cg(Xb + slot(tx)*XBs + (size_t)row*Dl + d, pk);
      }
      // ---- linear head, t = p-3: per WG m128 x n16 ----
      const int to = p - 3;
      if (to >= 0 && to < Tt) {
        const unsigned short* hA = h3r + slot(to)*HBs;
        const unsigned short* pa[2];
        #pragma unroll
        for (int mf = 0; mf < 2; ++mf) {
          const int row = wv*32 + mf*16 + l15;
          pa[mf] = hA + (size_t)row*Hb + klo;
        }
        const int rowbyte = l15*2048;
        const int xr = (l15 & 7) << 4;
        const int klobyte = klo*2;
        floatx4 oacc[2];
        {
          floatx4 b4 = {bias_r[0], bias_r[0], bias_r[0], bias_r[0]};
          oacc[0] = b4; oacc[1] = b4;
        }
        short8 A0[4][2], A1[4][2];
        auto HLOAD = [&](int c, short8 (&A)[4][2]) {
          #pragma unroll
          for (int ks = 0; ks < 4; ++ks)
            #pragma unroll
            for (int mf = 0; mf < 2; ++mf)
              A[ks][mf] = *(const short8*)(pa[mf] + c*128 + ks*32);
        };
        auto HMM = [&](int c, short8 (&A)[4][2]) {
          #pragma unroll
          for (int ks = 0; ks < 4; ++ks) {
            const int kb = c*128 + ks*32;
            short8 bw = *(const short8*)(smem + rowbyte + ((kb*2 + klobyte) ^ xr));
            #pragma unroll
            for (int mf = 0; mf < 2; ++mf)
              oacc[mf] = __builtin_amdgcn_mfma_f32_16x16x32_bf16(A[ks][mf], bw, oacc[mf], 0, 0, 0);
          }
        };
        HLOAD(0, A0);
        #pragma unroll 1
        for (int ch = 0; ch < 8; ch += 2) {
          HLOAD(ch + 1, A1);
          HMM(ch, A0);
          if (ch + 2 < 8) HLOAD(ch + 2, A0);
          HMM(ch + 1, A1);
        }
        const int col = osec + l15;
        #pragma unroll
        for (int mf = 0; mf < 2; ++mf) {
          const int b0 = wv*32 + mf*16 + ((lane >> 4) << 2);
          #pragma unroll
          for (int j = 0; j < 4; ++j)
            st_dword_cg(out + ((size_t)to*Bb + b0 + j)*Dl + col,
                        __float_as_uint(oacc[mf][j]));
        }
      }
    }

    // ---- grid barrier + periodic cache acquire ----
    if (p < NPHASE - 1) {
      waitcnt_vm0();
      __syncthreads();
      const unsigned int tgt = (unsigned int)(p + 1);
      if (tid == 0) st_dword_cg(flags + wg, tgt);
      if (tid < 64) {
        uintx4 f;
        for (;;) {
          asm volatile("global_load_dwordx4 %0, %1, off sc0 sc1\n\t"
                       "s_waitcnt vmcnt(0)"
                       : "=v"(f) : "v"(flags + lane*4) : "memory");
          if (f[0] >= tgt && f[1] >= tgt && f[2] >= tgt && f[3] >= tgt) break;
          __builtin_amdgcn_s_sleep(4);
        }
      }
      __syncthreads();
      // D==2: every phase (proven r5). D==8: end of every 8th phase — one fence falls in
      // [w+1, w+8] for every slot-write w, clearing all age-1 stale copies before reuse.
      if (D == 2 || (p & 7) == 7)
        __builtin_amdgcn_fence(__ATOMIC_ACQUIRE, "agent");
    }
  }
}

extern "C" void kernel_launch(void* const* d_in, const int* in_sizes, int n_in,
                              void* d_out, int out_size, void* d_ws, size_t ws_size,
                              hipStream_t stream)
{
  const float* X    = (const float*)d_in[0];
  const float* Wih1 = (const float*)d_in[1];
  const float* Whh1 = (const float*)d_in[2];
  const float* bih1 = (const float*)d_in[3];
  const float* bhh1 = (const float*)d_in[4];
  const float* Wih2 = (const float*)d_in[5];
  const float* Whh2 = (const float*)d_in[6];
  const float* bih2 = (const float*)d_in[7];
  const float* bhh2 = (const float*)d_in[8];
  const float* Wih3 = (const float*)d_in[9];
  const float* Whh3 = (const float*)d_in[10];
  const float* bih3 = (const float*)d_in[11];
  const float* bhh3 = (const float*)d_in[12];
  const float* Wlin = (const float*)d_in[13];
  const float* blin = (const float*)d_in[14];
  unsigned char* ws = (unsigned char*)d_ws;

  if (ws_size >= Lay<8>::END) {
    lstm_init<8><<<2048, 256, 0, stream>>>(X, Wih1, Whh1, bih1, bhh1,
                                           Wih2, Whh2, bih2, bhh2,
                                           Wih3, Whh3, bih3, bhh3,
                                           Wlin, blin, ws);
    lstm_persist<8><<<NWG, 256, 131072, stream>>>(X, (float*)d_out, ws);
  } else if (ws_size >= Lay<2>::END) {
    lstm_init<2><<<2048, 256, 0, stream>>>(X, Wih1, Whh1, bih1, bhh1,
                                           Wih2, Whh2, bih2, bhh2,
                                           Wih3, Whh3, bih3, bhh3,
                                           Wlin, blin, ws);
    lstm_persist<2><<<NWG, 256, 131072, stream>>>(X, (float*)d_out, ws);
  }
}

// Round 10
// 3951.132 us; speedup vs baseline: 1.8685x; 1.5761x over previous
//
#include <hip/hip_runtime.h>
#include <stdint.h>

#define NWG 208
#define NPHASE 259   // head t=255 at p=258

typedef __attribute__((ext_vector_type(8))) short short8;
typedef __attribute__((ext_vector_type(4))) float floatx4;
typedef __attribute__((ext_vector_type(4))) unsigned int uintx4;

static constexpr int Bb = 128, Tt = 256, Dl = 256, Hs = 512, Hb = 1024;

// ---- fixed workspace header ----
static constexpr size_t OFF_FLAGS = 0;                                   // u32[256]
static constexpr size_t OFF_B1  = 1024;
static constexpr size_t OFF_B2  = OFF_B1 + 2048*4;
static constexpr size_t OFF_B3  = OFF_B2 + 2048*4;
static constexpr size_t OFF_BL  = OFF_B3 + 4096*4;
static constexpr size_t OFF_W1  = OFF_BL + 1024;
static constexpr size_t OFF_W2  = OFF_W1 + (size_t)2048*768*2;
static constexpr size_t OFF_W3  = OFF_W2 + (size_t)2048*1024*2;
static constexpr size_t OFF_WL  = OFF_W3 + (size_t)4096*1536*2;
static constexpr size_t FIXED_END = OFF_WL + (size_t)256*1024*2;

// rings, depth D. Layout: fragment-blocked — block(u>>5, row>>4) of 512 shorts,
// within-block short offset = ((u&31)>>3)*128 + (row&15)*8 + (u&7).
// Slot sizes identical to row-major: h1/h2 = 128*512, h3 = 128*1024, x = 128*256 shorts.
template<int D> struct Lay {
  static constexpr size_t H1  = FIXED_END;
  static constexpr size_t H2  = H1 + (size_t)D*Bb*Hs*2;
  static constexpr size_t H3  = H2 + (size_t)D*Bb*Hs*2;
  static constexpr size_t XB  = H3 + (size_t)D*Bb*Hb*2;
  static constexpr size_t END = XB + (size_t)D*Bb*Dl*2;
};

__device__ __forceinline__ unsigned short f2bf(float f) {
  unsigned int u = __float_as_uint(f);
  unsigned int r = (u + 0x7fffu + ((u >> 16) & 1u)) >> 16;
  return (unsigned short)r;
}
__device__ __forceinline__ float sigm(float x) { return 1.f/(1.f + __expf(-x)); }
__device__ __forceinline__ float tanh_f(float x) {
  x = fminf(fmaxf(x, -15.f), 15.f);
  float e = __expf(-2.f*x);
  return (1.f - e)/(1.f + e);
}

// blocked-layout short offset for (row, u)
__device__ __forceinline__ size_t blk_off(int row, int u) {
  return ((size_t)(u >> 5)*8 + (row >> 4))*512 + (size_t)((u & 31) >> 3)*128
       + (size_t)(row & 15)*8 + (u & 7);
}

// coherent (write-through to LLC) stores; plain cached loads elsewhere
__device__ __forceinline__ void st_short_cg(unsigned short* p, unsigned int v) {
  asm volatile("global_store_short %0, %1, off sc0 sc1" :: "v"(p), "v"(v) : "memory");
}
__device__ __forceinline__ void st_dword_cg(void* p, unsigned int v) {
  asm volatile("global_store_dword %0, %1, off sc0 sc1" :: "v"(p), "v"(v) : "memory");
}
__device__ __forceinline__ void st_b128_cg(void* p, uintx4 v) {
  asm volatile("global_store_dwordx4 %0, %1, off sc0 sc1" :: "v"(p), "v"(v) : "memory");
}
__device__ __forceinline__ void waitcnt_vm0() {
  asm volatile("s_waitcnt vmcnt(0)" ::: "memory");
}

// ---------------- init ----------------
template<int D>
__global__ void lstm_init(
    const float* __restrict__ X,
    const float* __restrict__ Wih1, const float* __restrict__ Whh1,
    const float* __restrict__ bih1, const float* __restrict__ bhh1,
    const float* __restrict__ Wih2, const float* __restrict__ Whh2,
    const float* __restrict__ bih2, const float* __restrict__ bhh2,
    const float* __restrict__ Wih3, const float* __restrict__ Whh3,
    const float* __restrict__ bih3, const float* __restrict__ bhh3,
    const float* __restrict__ Wlin, const float* __restrict__ blin,
    unsigned char* __restrict__ ws)
{
  size_t i0 = (size_t)blockIdx.x*blockDim.x + threadIdx.x;
  size_t np = (size_t)gridDim.x*blockDim.x;

  unsigned int* fl = (unsigned int*)(ws + OFF_FLAGS);
  for (size_t i = i0; i < 256; i += np) fl[i] = (i < NWG) ? 0u : 0xFFFFFFFFu;

  float* b1 = (float*)(ws + OFF_B1);
  float* b2 = (float*)(ws + OFF_B2);
  float* b3 = (float*)(ws + OFF_B3);
  float* bl = (float*)(ws + OFF_BL);
  for (size_t i = i0; i < 2048; i += np) b1[i] = bih1[i] + bhh1[i];
  for (size_t i = i0; i < 2048; i += np) b2[i] = bih2[i] + bhh2[i];
  for (size_t i = i0; i < 4096; i += np) b3[i] = bih3[i] + bhh3[i];
  for (size_t i = i0; i < 256;  i += np) bl[i] = blin[i];

  unsigned short* w1 = (unsigned short*)(ws + OFF_W1);
  unsigned short* w2 = (unsigned short*)(ws + OFF_W2);
  unsigned short* w3 = (unsigned short*)(ws + OFF_W3);
  unsigned short* wl = (unsigned short*)(ws + OFF_WL);
  for (size_t i = i0; i < (size_t)2048*768; i += np) {
    size_t r = i/768, k = i - r*768;
    float v = (k < 256) ? Wih1[r*256 + k] : Whh1[r*512 + (k - 256)];
    w1[i] = f2bf(v);
  }
  for (size_t i = i0; i < (size_t)2048*1024; i += np) {
    size_t r = i >> 10, k = i & 1023;
    float v = (k < 512) ? Wih2[r*512 + k] : Whh2[r*512 + (k - 512)];
    w2[i] = f2bf(v);
  }
  for (size_t i = i0; i < (size_t)4096*1536; i += np) {
    size_t r = i/1536, k = i - r*1536;
    float v = (k < 512) ? Wih3[r*512 + k] : Whh3[r*1024 + (k - 512)];
    w3[i] = f2bf(v);
  }
  for (size_t i = i0; i < (size_t)256*1024; i += np) wl[i] = f2bf(Wlin[i]);

  // zero ALL ring slots (layout-agnostic)
  unsigned short* rings = (unsigned short*)(ws + Lay<D>::H1);
  const size_t nring = (size_t)D*Bb*Hs + (size_t)D*Bb*Hs + (size_t)D*Bb*Hb;
  for (size_t i = i0; i < nring; i += np) rings[i] = 0;

  // stage x(t=0) into XB slot 0 (BLOCKED layout)
  unsigned short* xb0 = (unsigned short*)(ws + Lay<D>::XB);
  for (size_t i = i0; i < (size_t)Bb*Dl; i += np) {
    size_t b = i >> 8, d = i & 255;
    xb0[blk_off((int)b, (int)d)] = f2bf(X[(b*(size_t)Tt + 0)*Dl + d]);
  }
}

// ---------------- per-layer phase: blocked A-loads (coalesced), r8 math ----------------
// TYPE0 (L1): K=768, segA=XB(KB1=256), segB=h1; MF=4
// TYPE1 (L2): K=1024, segA=h1(KB1=512), segB=h2; MF=4
// TYPE2 (L3): K=1536, segA=h2(KB1=512), segB=h3; MF=2
template<int TYPE>
__device__ __forceinline__ void layer_phase(
    const unsigned short* __restrict__ segA,
    const unsigned short* __restrict__ segB,
    unsigned short* __restrict__ hout,
    const unsigned char* __restrict__ smem,
    const float* __restrict__ bias_r,
    float (&creg)[4][2][4],
    int U0, int wv, int lane)
{
  constexpr int K    = (TYPE==0 ? 768 : TYPE==1 ? 1024 : 1536);
  constexpr int KB1  = (TYPE==0 ? 256 : 512);
  constexpr int MF   = (TYPE==2 ? 2 : 4);
  constexpr int NCH  = K/128;
  const int l15 = lane & 15;
  const int klo = (lane >> 4) << 3;
  const int g   = l15 >> 2;
  const int mbase = (TYPE==2 ? wv*32 : (wv&1)*64);
  const int nfb   = (TYPE==2 ? 0 : (wv>>1)*2);

  // blocked A pointers: lane offset within 1KB block, + row-block base
  const size_t lof = (size_t)(lane >> 4)*128 + (size_t)l15*8;
  const unsigned short* pa[MF];
  const unsigned short* pb[MF];
  #pragma unroll
  for (int mf = 0; mf < MF; ++mf) {
    const size_t rb = (size_t)((mbase >> 4) + mf)*512;
    pa[mf] = segA + rb + lof;
    pb[mf] = segB + rb + lof;
  }
  int rowbyte[2], xr[2];
  #pragma unroll
  for (int nf = 0; nf < 2; ++nf) {
    const int rp = (nfb + nf)*16 + l15;
    rowbyte[nf] = rp*(K*2);
    xr[nf] = (rp & 7) << 4;
  }
  const int klobyte = klo*2;

  floatx4 acc[MF][2];
  #pragma unroll
  for (int mf = 0; mf < MF; ++mf)
    #pragma unroll
    for (int nf = 0; nf < 2; ++nf) {
      float bv = bias_r[nf];
      floatx4 b4 = {bv, bv, bv, bv};
      acc[mf][nf] = b4;
    }

  short8 A0[4][MF], A1[4][MF];
  auto LOADC = [&](int c, short8 (&A)[4][MF]) {
    #pragma unroll
    for (int ks = 0; ks < 4; ++ks) {
      const int kb = c*128 + ks*32;
      #pragma unroll
      for (int mf = 0; mf < MF; ++mf) {
        const unsigned short* p = (kb < KB1)
            ? pa[mf] + (size_t)(kb >> 5)*4096
            : pb[mf] + (size_t)((kb - KB1) >> 5)*4096;
        A[ks][mf] = *(const short8*)p;
      }
    }
  };
  auto MM = [&](int c, short8 (&A)[4][MF]) {
    #pragma unroll
    for (int ks = 0; ks < 4; ++ks) {
      const int kb = c*128 + ks*32;
      short8 bf[2];
      #pragma unroll
      for (int nf = 0; nf < 2; ++nf)
        bf[nf] = *(const short8*)(smem + rowbyte[nf] + ((kb*2 + klobyte) ^ xr[nf]));
      #pragma unroll
      for (int mf = 0; mf < MF; ++mf)
        #pragma unroll
        for (int nf = 0; nf < 2; ++nf)
          acc[mf][nf] = __builtin_amdgcn_mfma_f32_16x16x32_bf16(A[ks][mf], bf[nf], acc[mf][nf], 0, 0, 0);
    }
  };

  LOADC(0, A0);
  #pragma unroll 1
  for (int ch = 0; ch < NCH; ch += 2) {
    LOADC(ch + 1, A1);
    MM(ch, A0);
    if (ch + 2 < NCH) LOADC(ch + 2, A0);
    MM(ch + 1, A1);
  }

  // cell update (r8 math); h store at blocked offset
  #pragma unroll
  for (int nf = 0; nf < 2; ++nf) {
    const int u = U0 + (nfb + nf)*4 + (l15 & 3);
    #pragma unroll
    for (int mf = 0; mf < MF; ++mf) {
      float h4[4];
      #pragma unroll
      for (int j = 0; j < 4; ++j) {
        float s0  = acc[mf][nf][j];
        float s4  = __shfl_xor(s0, 4);
        float s8  = __shfl_xor(s0, 8);
        float s12 = __shfl_xor(s0, 12);
        float iv = (g==0)?s0 :(g==1)?s4 :(g==2)?s8 :s12;
        float fv = (g==0)?s4 :(g==1)?s0 :(g==2)?s12:s8;
        float gv = (g==0)?s8 :(g==1)?s12:(g==2)?s0 :s4;
        float ov = (g==0)?s12:(g==1)?s8 :(g==2)?s4 :s0;
        float c  = sigm(fv)*creg[mf][nf][j] + sigm(iv)*tanh_f(gv);
        creg[mf][nf][j] = c;
        h4[j] = sigm(ov)*tanh_f(c);
      }
      float hs = (g==0)?h4[0]:(g==1)?h4[1]:(g==2)?h4[2]:h4[3];
      const int row = mbase + mf*16 + ((lane >> 4) << 2) + g;
      st_short_cg(hout + blk_off(row, u), (unsigned int)f2bf(hs));
    }
  }
}

// ---------------- persistent kernel ----------------
// wg 0..31: L1 (t=p) | 32..63: L2 (t=p-1) | 64..191: L3 (t=p-2) | 192..207: head (t=p-3) + x-stage (p+1)
template<int D>
__global__ void __launch_bounds__(256, 1)
lstm_persist(const float* __restrict__ X, float* __restrict__ out,
             unsigned char* __restrict__ ws)
{
  extern __shared__ unsigned char smem[];

  __builtin_amdgcn_fence(__ATOMIC_ACQUIRE, "agent");  // clear pre-dispatch stale lines once

  const int tid  = threadIdx.x;
  const int lane = tid & 63;
  const int wv   = tid >> 6;
  const int wg   = blockIdx.x;
  const int l15  = lane & 15;

  unsigned int* flags = (unsigned int*)(ws + OFF_FLAGS);
  const float* bias1 = (const float*)(ws + OFF_B1);
  const float* bias2 = (const float*)(ws + OFF_B2);
  const float* bias3 = (const float*)(ws + OFF_B3);
  const float* biasl = (const float*)(ws + OFF_BL);
  const unsigned short* W1 = (const unsigned short*)(ws + OFF_W1);
  const unsigned short* W2 = (const unsigned short*)(ws + OFF_W2);
  const unsigned short* W3 = (const unsigned short*)(ws + OFF_W3);
  const unsigned short* WL = (const unsigned short*)(ws + OFF_WL);
  unsigned short* h1r = (unsigned short*)(ws + Lay<D>::H1);
  unsigned short* h2r = (unsigned short*)(ws + Lay<D>::H2);
  unsigned short* h3r = (unsigned short*)(ws + Lay<D>::H3);
  unsigned short* Xb  = (unsigned short*)(ws + Lay<D>::XB);

  auto slot = [](int t) -> size_t { return (size_t)(t & (D - 1)); };
  const size_t HSs = (size_t)Bb*Hs, HBs = (size_t)Bb*Hb, XBs = (size_t)Bb*Dl;

  // role decode
  int type, U0 = 0, osec = 0, K = 0, WROWS = 0, HGATE = 0;
  const unsigned short* Wg = nullptr; const float* biasp = nullptr;
  if (wg < 32)        { type = 0; U0 = wg*16;        Wg = W1; biasp = bias1; K = 768;  WROWS = 64; HGATE = 512; }
  else if (wg < 64)   { type = 1; U0 = (wg-32)*16;   Wg = W2; biasp = bias2; K = 1024; WROWS = 64; HGATE = 512; }
  else if (wg < 192)  { type = 2; U0 = (wg-64)*8;    Wg = W3; biasp = bias3; K = 1536; WROWS = 32; HGATE = 1024; }
  else                { type = 3; osec = (wg-192)*16; Wg = WL; K = 1024; WROWS = 16; }

  // prologue: weight slice -> LDS (packed rows: quad=4 units x 4 gates), XOR-swizzled
  {
    const int rowchunks = K >> 3;
    for (int idx = tid; idx < WROWS*rowchunks; idx += 256) {
      const int rp = idx / rowchunks, kc = idx - rp*rowchunks;
      int R;
      if (type == 3) R = osec + rp;
      else {
        const int c = rp & 15;
        R = (c >> 2)*HGATE + U0 + (rp >> 4)*4 + (c & 3);
      }
      uintx4 v = *(const uintx4*)(Wg + (size_t)R*K + kc*8);
      const int db = rp*(K*2) + ((kc*16) ^ ((rp & 7) << 4));
      *(uintx4*)(smem + db) = v;
    }
  }

  // per-lane bias preload
  float bias_r[2] = {0.f, 0.f};
  if (type < 3) {
    const int g   = l15 >> 2;
    const int nfb = (type == 2 ? 0 : (wv >> 1)*2);
    #pragma unroll
    for (int nf = 0; nf < 2; ++nf) {
      const int u = U0 + (nfb + nf)*4 + (l15 & 3);
      bias_r[nf] = biasp[g*HGATE + u];
    }
  } else {
    bias_r[0] = biasl[osec + l15];
  }

  float creg[4][2][4];
  #pragma unroll
  for (int a = 0; a < 4; ++a)
    #pragma unroll
    for (int b = 0; b < 2; ++b)
      #pragma unroll
      for (int c = 0; c < 4; ++c) creg[a][b][c] = 0.f;

  __syncthreads();

  for (int p = 0; p < NPHASE; ++p) {
    if (type == 0) {
      const int t = p;
      if (t < Tt)
        layer_phase<0>(Xb + slot(t)*XBs,
                       h1r + slot(t-1)*HSs,
                       h1r + slot(t)*HSs,
                       smem, bias_r, creg, U0, wv, lane);
    } else if (type == 1) {
      const int t = p - 1;
      if (t >= 0 && t < Tt)
        layer_phase<1>(h1r + slot(t)*HSs,
                       h2r + slot(t-1)*HSs,
                       h2r + slot(t)*HSs,
                       smem, bias_r, creg, U0, wv, lane);
    } else if (type == 2) {
      const int t = p - 2;
      if (t >= 0 && t < Tt)
        layer_phase<2>(h2r + slot(t)*HSs,
                       h3r + slot(t-1)*HBs,
                       h3r + slot(t)*HBs,
                       smem, bias_r, creg, U0, wv, lane);
    } else {
      // ---- x staging for t = p+1 (BLOCKED layout; one 16B slot per thread) ----
      if (p + 1 < Tt) {
        const int tx = p + 1;
        const int j = wg - 192;
        const int i = tid*8;
        const int row = j*8 + (i >> 8);
        const int d = i & 255;
        const float* xp = X + ((size_t)row*Tt + tx)*Dl + d;
        float4 f0 = *(const float4*)xp;
        float4 f1 = *(const float4*)(xp + 4);
        uintx4 pk;
        pk[0] = (unsigned int)f2bf(f0.x) | ((unsigned int)f2bf(f0.y) << 16);
        pk[1] = (unsigned int)f2bf(f0.z) | ((unsigned int)f2bf(f0.w) << 16);
        pk[2] = (unsigned int)f2bf(f1.x) | ((unsigned int)f2bf(f1.y) << 16);
        pk[3] = (unsigned int)f2bf(f1.z) | ((unsigned int)f2bf(f1.w) << 16);
        st_b128_cg(Xb + slot(tx)*XBs + blk_off(row, d), pk);
      }
      // ---- linear head, t = p-3: per WG m128 x n16, blocked h3 reads ----
      const int to = p - 3;
      if (to >= 0 && to < Tt) {
        const unsigned short* hA = h3r + slot(to)*HBs;
        const size_t lof = (size_t)(lane >> 4)*128 + (size_t)l15*8;
        const unsigned short* pa[2];
        #pragma unroll
        for (int mf = 0; mf < 2; ++mf)
          pa[mf] = hA + (size_t)((wv*32 + mf*16) >> 4)*512 + lof;
        const int rowbyte = l15*2048;
        const int xr = (l15 & 7) << 4;
        const int klobyte = ((lane >> 4) << 3)*2;
        floatx4 oacc[2];
        {
          floatx4 b4 = {bias_r[0], bias_r[0], bias_r[0], bias_r[0]};
          oacc[0] = b4; oacc[1] = b4;
        }
        short8 A0[4][2], A1[4][2];
        auto HLOAD = [&](int c, short8 (&A)[4][2]) {
          #pragma unroll
          for (int ks = 0; ks < 4; ++ks)
            #pragma unroll
            for (int mf = 0; mf < 2; ++mf)
              A[ks][mf] = *(const short8*)(pa[mf] + (size_t)(c*4 + ks)*4096);
        };
        auto HMM = [&](int c, short8 (&A)[4][2]) {
          #pragma unroll
          for (int ks = 0; ks < 4; ++ks) {
            const int kb = c*128 + ks*32;
            short8 bw = *(const short8*)(smem + rowbyte + ((kb*2 + klobyte) ^ xr));
            #pragma unroll
            for (int mf = 0; mf < 2; ++mf)
              oacc[mf] = __builtin_amdgcn_mfma_f32_16x16x32_bf16(A[ks][mf], bw, oacc[mf], 0, 0, 0);
          }
        };
        HLOAD(0, A0);
        #pragma unroll 1
        for (int ch = 0; ch < 8; ch += 2) {
          HLOAD(ch + 1, A1);
          HMM(ch, A0);
          if (ch + 2 < 8) HLOAD(ch + 2, A0);
          HMM(ch + 1, A1);
        }
        const int col = osec + l15;
        #pragma unroll
        for (int mf = 0; mf < 2; ++mf) {
          const int b0 = wv*32 + mf*16 + ((lane >> 4) << 2);
          #pragma unroll
          for (int j = 0; j < 4; ++j)
            st_dword_cg(out + ((size_t)to*Bb + b0 + j)*Dl + col,
                        __float_as_uint(oacc[mf][j]));
        }
      }
    }

    // ---- grid barrier + periodic cache acquire (r8 protocol) ----
    if (p < NPHASE - 1) {
      waitcnt_vm0();
      __syncthreads();
      const unsigned int tgt = (unsigned int)(p + 1);
      if (tid == 0) st_dword_cg(flags + wg, tgt);
      if (tid < 64) {
        uintx4 f;
        for (;;) {
          asm volatile("global_load_dwordx4 %0, %1, off sc0 sc1\n\t"
                       "s_waitcnt vmcnt(0)"
                       : "=v"(f) : "v"(flags + lane*4) : "memory");
          if (f[0] >= tgt && f[1] >= tgt && f[2] >= tgt && f[3] >= tgt) break;
          __builtin_amdgcn_s_sleep(4);
        }
      }
      __syncthreads();
      if (D == 2 || (p & 7) == 7)
        __builtin_amdgcn_fence(__ATOMIC_ACQUIRE, "agent");
    }
  }
}

extern "C" void kernel_launch(void* const* d_in, const int* in_sizes, int n_in,
                              void* d_out, int out_size, void* d_ws, size_t ws_size,
                              hipStream_t stream)
{
  const float* X    = (const float*)d_in[0];
  const float* Wih1 = (const float*)d_in[1];
  const float* Whh1 = (const float*)d_in[2];
  const float* bih1 = (const float*)d_in[3];
  const float* bhh1 = (const float*)d_in[4];
  const float* Wih2 = (const float*)d_in[5];
  const float* Whh2 = (const float*)d_in[6];
  const float* bih2 = (const float*)d_in[7];
  const float* bhh2 = (const float*)d_in[8];
  const float* Wih3 = (const float*)d_in[9];
  const float* Whh3 = (const float*)d_in[10];
  const float* bih3 = (const float*)d_in[11];
  const float* bhh3 = (const float*)d_in[12];
  const float* Wlin = (const float*)d_in[13];
  const float* blin = (const float*)d_in[14];
  unsigned char* ws = (unsigned char*)d_ws;

  if (ws_size >= Lay<8>::END) {
    lstm_init<8><<<2048, 256, 0, stream>>>(X, Wih1, Whh1, bih1, bhh1,
                                           Wih2, Whh2, bih2, bhh2,
                                           Wih3, Whh3, bih3, bhh3,
                                           Wlin, blin, ws);
    lstm_persist<8><<<NWG, 256, 131072, stream>>>(X, (float*)d_out, ws);
  } else if (ws_size >= Lay<2>::END) {
    lstm_init<2><<<2048, 256, 0, stream>>>(X, Wih1, Whh1, bih1, bhh1,
                                           Wih2, Whh2, bih2, bhh2,
                                           Wih3, Whh3, bih3, bhh3,
                                           Wlin, blin, ws);
    lstm_persist<2><<<NWG, 256, 131072, stream>>>(X, (float*)d_out, ws);
  }
}